// Round 1
// baseline (134.485 us; speedup 1.0000x reference)
//
#include <hip/hip_runtime.h>

// SDConv: out[b,o,h,w] = sum_{c,ki,kj} weight[o,c,ki,kj] * S * u_diff
//   u_diff = U[neighbor] - U[center] (zero-padded neighborhood)
//   S      = rsqrt(1 + (V[neighbor] - V[center])^2)   (LAMBDA = 1)
// Center tap (ki=kj=1) contributes 0 -> skipped.

constexpr int Bn = 8, Ci = 16, Co = 16, H = 224, W = 224;
constexpr int HW = H * W;
constexpr int TW = 32, TH = 8;   // 32x8 pixel tile per 256-thread block

// Load the 3x3 zero-padded neighborhood of (h,w) from plane p (p points at (h,w)).
template <bool EDGE>
__device__ __forceinline__ void load_nbhd(const float* __restrict__ p,
                                          int h, int w, float out9[9]) {
#pragma unroll
  for (int dh = 0; dh < 3; ++dh) {
#pragma unroll
    for (int dw = 0; dw < 3; ++dw) {
      const int k = dh * 3 + dw;
      if (!EDGE) {
        // interior: compile-time offsets fold into load immediates
        out9[k] = p[(dh - 1) * W + (dw - 1)];
      } else {
        const int hh = h + dh - 1, ww = w + dw - 1;
        const bool ok = ((unsigned)hh < (unsigned)H) & ((unsigned)ww < (unsigned)W);
        const int off = ok ? ((dh - 1) * W + (dw - 1)) : 0;  // clamp to safe addr
        const float val = p[off];
        out9[k] = ok ? val : 0.0f;   // zero padding
      }
    }
  }
}

template <bool EDGE>
__device__ __forceinline__ void compute_pixel(
    const float* __restrict__ U, const float* __restrict__ V,
    float* __restrict__ Out, int b, int h, int w,
    const float (*__restrict__ wt)[9][Co]) {
  float acc[Co];
#pragma unroll
  for (int o = 0; o < Co; ++o) acc[o] = 0.0f;

  const size_t pix = (size_t)h * W + w;
  const float* up0 = U + (size_t)b * Ci * HW + pix;
  const float* vp0 = V + (size_t)b * Ci * HW + pix;

  for (int c = 0; c < Ci; ++c) {
    const float* up = up0 + c * HW;
    const float* vp = vp0 + c * HW;
    float u[9], v[9];
    load_nbhd<EDGE>(up, h, w, u);
    load_nbhd<EDGE>(vp, h, w, v);
    const float uc = u[4], vc = v[4];

    float t[9];
#pragma unroll
    for (int k = 0; k < 9; ++k) {
      if (k == 4) continue;
      const float vd = v[k] - vc;
      const float s = rsqrtf(fmaf(vd, vd, 1.0f));  // LAMBDA=1 -> inv_l2=1
      t[k] = s * (u[k] - uc);
    }

    // acc[o] += wt[c][k][o] * t[k]; weights in LDS, [c][k][o] layout,
    // uniform-address ds_read_b128 broadcasts 4 o-weights per read.
#pragma unroll
    for (int k = 0; k < 9; ++k) {
      if (k == 4) continue;
      const float tk = t[k];
#pragma unroll
      for (int o = 0; o < Co; o += 4) {
        const float4 wv = *reinterpret_cast<const float4*>(&wt[c][k][o]);
        acc[o + 0] = fmaf(wv.x, tk, acc[o + 0]);
        acc[o + 1] = fmaf(wv.y, tk, acc[o + 1]);
        acc[o + 2] = fmaf(wv.z, tk, acc[o + 2]);
        acc[o + 3] = fmaf(wv.w, tk, acc[o + 3]);
      }
    }
  }

  float* op = Out + (size_t)b * Co * HW + pix;
#pragma unroll
  for (int o = 0; o < Co; ++o) op[(size_t)o * HW] = acc[o];
}

__global__ __launch_bounds__(256)
void sdconv_kernel(const float* __restrict__ U, const float* __restrict__ V,
                   const float* __restrict__ Wg, float* __restrict__ Out) {
  // Stage weight transposed to [c][k][o] so the 16 o-weights are contiguous.
  __shared__ float wt[Ci][9][Co];
  for (int i = threadIdx.x; i < Co * Ci * 9; i += 256) {
    const int k = i % 9;
    const int c = (i / 9) % Ci;
    const int o = i / (9 * Ci);
    wt[c][k][o] = Wg[i];
  }
  __syncthreads();

  const int tw = threadIdx.x & (TW - 1);
  const int th = threadIdx.x / TW;
  const int w = blockIdx.x * TW + tw;
  const int h = blockIdx.y * TH + th;
  const int b = blockIdx.z;

  const bool edge = (blockIdx.x == 0) | (blockIdx.x == gridDim.x - 1) |
                    (blockIdx.y == 0) | (blockIdx.y == gridDim.y - 1);
  if (edge)
    compute_pixel<true>(U, V, Out, b, h, w, wt);
  else
    compute_pixel<false>(U, V, Out, b, h, w, wt);
}

extern "C" void kernel_launch(void* const* d_in, const int* in_sizes, int n_in,
                              void* d_out, int out_size, void* d_ws, size_t ws_size,
                              hipStream_t stream) {
  const float* U  = (const float*)d_in[0];
  const float* V  = (const float*)d_in[1];
  const float* Wg = (const float*)d_in[2];
  float* Out = (float*)d_out;

  dim3 grid(W / TW, H / TH, Bn);  // 7 x 28 x 8
  dim3 block(TW * TH);            // 256
  sdconv_kernel<<<grid, block, 0, stream>>>(U, V, Wg, Out);
}

// Round 4
// 125.708 us; speedup vs baseline: 1.0698x; 1.0698x over previous
//
#include <hip/hip_runtime.h>

// SDConv via MFMA: out[b,o,h,w] = sum_{c,tap} weight[o,c,tap] * t[c,tap]
//   t = rsqrt(1 + (V[nb]-V[c])^2) * (U[nb]-U[c]),  zero-padded neighborhoods,
//   center tap contributes 0 (skipped) -> K = 16 channels * 8 taps = 128.
// Per-pixel einsum mapped to v_mfma_f32_16x16x32_f16:
//   A[16 px][32 k] : lane computes t for pixel (lane&15), channel 4*kc+(lane>>4)
//   B[32 k][16 o]  : lane holds weights for o=(lane&15), channel 4*kc+(lane>>4)
//   (A and B use the same (lane-group, elem)->k map, so the exact HW k
//    permutation cancels in the dot product.)
//   D: col(o)=lane&15, row(px)=(lane>>4)*4+reg  [m89-verified]

constexpr int Bn = 8, Ci = 16, Co = 16, H = 224, W = 224;
constexpr int HW = H * W;

typedef _Float16 f16x8 __attribute__((ext_vector_type(8)));
typedef float    f32x4 __attribute__((ext_vector_type(4)));

// Load {w-1, w, w+1} of row h from a plane. Interior: constant-offset loads.
template <bool EDGE>
__device__ __forceinline__ void load_row(const float* __restrict__ plane,
                                         int h, int w, float r[3]) {
  if (!EDGE) {
    const float* q = plane + h * W + w;
    r[0] = q[-1]; r[1] = q[0]; r[2] = q[1];
  } else {
    if ((unsigned)h < (unsigned)H) {       // wave-uniform branch
      const float* q = plane + h * W + w;
      r[0] = (w >= 1)     ? q[-1] : 0.0f;  // per-lane exec-masked load
      r[1] = q[0];
      r[2] = (w + 1 < W) ? q[1] : 0.0f;
    } else {
      r[0] = 0.0f; r[1] = 0.0f; r[2] = 0.0f;
    }
  }
}

template <bool EDGE>
__device__ __forceinline__ void sdconv_wave(
    const float* __restrict__ U, const float* __restrict__ V,
    const float* __restrict__ Wg, float* __restrict__ Out,
    int b, int h0, int w0, int lane) {
  const int px = lane & 15;   // pixel index within the 16-wide tile; also o for B/D
  const int cg = lane >> 4;   // 0..3 : channel sub-group

  const int w = w0 + px;

  // ---- B fragments (weights), built once; 16 VGPRs total ----
  f16x8 bfrag[4];
#pragma unroll
  for (int kc = 0; kc < 4; ++kc) {
    const int c = 4 * kc + cg;
    const float* wp = Wg + (px * Ci + c) * 9;   // px plays the role of o here
#pragma unroll
    for (int j = 0; j < 8; ++j) {
      const int tap = (j < 4) ? j : j + 1;      // skip center tap (index 4)
      bfrag[kc][j] = (_Float16)wp[tap];
    }
  }

  f32x4 d[4];
#pragma unroll
  for (int r = 0; r < 4; ++r) { d[r][0] = 0.f; d[r][1] = 0.f; d[r][2] = 0.f; d[r][3] = 0.f; }

#pragma unroll
  for (int kc = 0; kc < 4; ++kc) {
    const int c = 4 * kc + cg;
    const float* up = U + ((size_t)(b * Ci + c)) * HW;
    const float* vp = V + ((size_t)(b * Ci + c)) * HW;

    // rolling 3-row window: rows h-1, h, h+1 for the current pixel row
    float u[3][3], v[3][3];
    load_row<EDGE>(up, h0 - 1, w, u[0]);
    load_row<EDGE>(vp, h0 - 1, w, v[0]);
    load_row<EDGE>(up, h0,     w, u[1]);
    load_row<EDGE>(vp, h0,     w, v[1]);

#pragma unroll
    for (int r = 0; r < 4; ++r) {
      load_row<EDGE>(up, h0 + r + 1, w, u[2]);
      load_row<EDGE>(vp, h0 + r + 1, w, v[2]);

      const float uc = u[1][1], vc = v[1][1];
      f16x8 a;
      int j = 0;
#pragma unroll
      for (int dh = 0; dh < 3; ++dh) {
#pragma unroll
        for (int dw = 0; dw < 3; ++dw) {
          if (dh == 1 && dw == 1) continue;
          const float vd = v[dh][dw] - vc;
          const float s  = rsqrtf(fmaf(vd, vd, 1.0f));   // LAMBDA = 1
          a[j++] = (_Float16)(s * (u[dh][dw] - uc));
        }
      }
      d[r] = __builtin_amdgcn_mfma_f32_16x16x32_f16(a, bfrag[kc], d[r], 0, 0, 0);

      // rotate window down one row
#pragma unroll
      for (int i = 0; i < 3; ++i) {
        u[0][i] = u[1][i]; u[1][i] = u[2][i];
        v[0][i] = v[1][i]; v[1][i] = v[2][i];
      }
    }
  }

  // ---- store: lane holds D[px = 4*cg + rr][o = px-index], 4 consecutive w ----
  const int wst = w0 + 4 * cg;                  // 16B-aligned (w0%16==0)
  const int o   = px;
#pragma unroll
  for (int r = 0; r < 4; ++r) {
    float* op = Out + (((size_t)b * Co + o) * H + (h0 + r)) * W + wst;
    *reinterpret_cast<f32x4*>(op) = d[r];
  }
}

__global__ __launch_bounds__(128)
void sdconv_mfma(const float* __restrict__ U, const float* __restrict__ V,
                 const float* __restrict__ Wg, float* __restrict__ Out) {
  const int lane = threadIdx.x & 63;
  const int wv   = threadIdx.x >> 6;            // 0..1
  const int w0 = blockIdx.x * 16;
  const int h0 = blockIdx.y * 8 + wv * 4;       // wave's first pixel row
  const int b  = blockIdx.z;

  const bool edge = (blockIdx.x == 0) | (blockIdx.x == gridDim.x - 1) |
                    (blockIdx.y == 0) | (blockIdx.y == gridDim.y - 1);
  if (edge)
    sdconv_wave<true >(U, V, Wg, Out, b, h0, w0, lane);
  else
    sdconv_wave<false>(U, V, Wg, Out, b, h0, w0, lane);
}

extern "C" void kernel_launch(void* const* d_in, const int* in_sizes, int n_in,
                              void* d_out, int out_size, void* d_ws, size_t ws_size,
                              hipStream_t stream) {
  const float* U  = (const float*)d_in[0];
  const float* V  = (const float*)d_in[1];
  const float* Wg = (const float*)d_in[2];
  float* Out = (float*)d_out;

  dim3 grid(W / 16, H / 8, Bn);   // 14 x 28 x 8 = 3136 blocks
  dim3 block(128);                // 2 waves; each wave: 16w x 4h pixels
  sdconv_mfma<<<grid, block, 0, stream>>>(U, V, Wg, Out);
}

// Round 6
// 119.780 us; speedup vs baseline: 1.1228x; 1.0495x over previous
//
#include <hip/hip_runtime.h>

// SDConv via MFMA: out[b,o,h,w] = sum_{c,tap} weight[o,c,tap] * t[c,tap]
//   t = rsqrt(1 + (V[nb]-V[c])^2) * (U[nb]-U[c]), zero-padded neighborhoods,
//   center tap contributes 0 -> K = 16 ch * 8 taps = 128.
// v_mfma_f32_16x16x32_f16 mapping (A and B share the same (lane-group, elem)
// -> (c,tap) rule, so the HW k-permutation cancels):
//   A[16 px][32 k]: lane computes t for pixel (lane&15), channel 4*kc+(lane>>4)
//   B[32 k][16 o] : lane holds weights for o=(lane&15), channel 4*kc+(lane>>4)
//   D: o=lane&15, px=(lane>>4)*4+reg  [m89-verified]
// Round-4 restructure: 8 rows/wave (16x16 block tile), all-4-kc loads issued
// before compute each row-step (4 independent latency chains), mod-3 rolling
// window with compile-time slots, raw v_rsq_f32.

constexpr int Bn = 8, Ci = 16, Co = 16, H = 224, W = 224;
constexpr int HW = H * W;
constexpr int ROWS = 8;   // pixel rows per wave

typedef _Float16 f16x8 __attribute__((ext_vector_type(8)));
typedef float    f32x4 __attribute__((ext_vector_type(4)));

// Load {w-1, w, w+1} of row h. Interior: constant-offset loads.
template <bool EDGE>
__device__ __forceinline__ void load_row(const float* __restrict__ plane,
                                         int h, int w, float* __restrict__ r) {
  if (!EDGE) {
    const float* q = plane + h * W + w;
    r[0] = q[-1]; r[1] = q[0]; r[2] = q[1];
  } else {
    if ((unsigned)h < (unsigned)H) {       // wave-uniform branch
      const float* q = plane + h * W + w;
      r[0] = (w >= 1)     ? q[-1] : 0.0f;  // per-lane exec-masked
      r[1] = q[0];
      r[2] = (w + 1 < W) ? q[1] : 0.0f;
    } else {
      r[0] = 0.0f; r[1] = 0.0f; r[2] = 0.0f;
    }
  }
}

template <bool EDGE>
__device__ __forceinline__ void sdconv_wave(
    const float* __restrict__ U, const float* __restrict__ V,
    const float* __restrict__ Wg, float* __restrict__ Out,
    int b, int h0, int w0, int lane) {
  const int px = lane & 15;   // pixel (w) index in tile; also o for B/D
  const int cg = lane >> 4;   // channel sub-group 0..3
  const int w  = w0 + px;

  // ---- B fragments (weights), built once ----
  f16x8 bfrag[4];
#pragma unroll
  for (int kc = 0; kc < 4; ++kc) {
    const int c = 4 * kc + cg;
    const float* wp = Wg + (px * Ci + c) * 9;   // px plays the role of o
#pragma unroll
    for (int j = 0; j < 8; ++j) {
      const int tap = (j < 4) ? j : j + 1;      // skip center tap
      bfrag[kc][j] = (_Float16)wp[tap];
    }
  }

  f32x4 d[ROWS];
#pragma unroll
  for (int r = 0; r < ROWS; ++r) d[r] = (f32x4){0.f, 0.f, 0.f, 0.f};

  const float* up[4];
  const float* vp[4];
#pragma unroll
  for (int kc = 0; kc < 4; ++kc) {
    const int c = 4 * kc + cg;
    up[kc] = U + ((size_t)(b * Ci + c)) * HW;
    vp[kc] = V + ((size_t)(b * Ci + c)) * HW;
  }

  // rolling 3-row windows per kc, mod-3 slots (all indices compile-time)
  float u[4][3][3], v[4][3][3];
#pragma unroll
  for (int kc = 0; kc < 4; ++kc) {
    load_row<EDGE>(up[kc], h0 - 1, w, u[kc][0]);
    load_row<EDGE>(vp[kc], h0 - 1, w, v[kc][0]);
    load_row<EDGE>(up[kc], h0,     w, u[kc][1]);
    load_row<EDGE>(vp[kc], h0,     w, v[kc][1]);
  }

#pragma unroll
  for (int r = 0; r < ROWS; ++r) {
    const int st = r % 3;         // top    = row h0+r-1
    const int sm = (r + 1) % 3;   // mid    = row h0+r
    const int sb = (r + 2) % 3;   // bottom = row h0+r+1 (loaded now)

    // issue ALL loads of this row-step first: 4 independent chains in flight
#pragma unroll
    for (int kc = 0; kc < 4; ++kc) {
      load_row<EDGE>(up[kc], h0 + r + 1, w, u[kc][sb]);
      load_row<EDGE>(vp[kc], h0 + r + 1, w, v[kc][sb]);
    }

#pragma unroll
    for (int kc = 0; kc < 4; ++kc) {
      const float uc = u[kc][sm][1], vc = v[kc][sm][1];
      const int slot[3] = {st, sm, sb};
      f16x8 a;
      int j = 0;
#pragma unroll
      for (int dh = 0; dh < 3; ++dh) {
#pragma unroll
        for (int dw = 0; dw < 3; ++dw) {
          if (dh == 1 && dw == 1) continue;
          const float vd = v[kc][slot[dh]][dw] - vc;
          const float s  = __builtin_amdgcn_rsqf(fmaf(vd, vd, 1.0f)); // LAMBDA=1
          a[j++] = (_Float16)(s * (u[kc][slot[dh]][dw] - uc));
        }
      }
      d[r] = __builtin_amdgcn_mfma_f32_16x16x32_f16(a, bfrag[kc], d[r], 0, 0, 0);
    }
  }

  // ---- store: lane holds D[px=4*cg+r'][o=px-index], 4 consecutive w ----
  const int wst = w0 + 4 * cg;    // 16B-aligned (w0 % 16 == 0)
  const int o   = px;
#pragma unroll
  for (int r = 0; r < ROWS; ++r) {
    float* op = Out + (((size_t)b * Co + o) * H + (h0 + r)) * W + wst;
    *reinterpret_cast<f32x4*>(op) = d[r];
  }
}

__global__ __launch_bounds__(128)
void sdconv_mfma(const float* __restrict__ U, const float* __restrict__ V,
                 const float* __restrict__ Wg, float* __restrict__ Out) {
  const int lane = threadIdx.x & 63;
  const int wv   = threadIdx.x >> 6;            // 0..1
  const int w0 = blockIdx.x * 16;
  const int h0 = blockIdx.y * 16 + wv * ROWS;   // wave's first pixel row
  const int b  = blockIdx.z;

  const bool edge = (blockIdx.x == 0) | (blockIdx.x == gridDim.x - 1) |
                    (blockIdx.y == 0) | (blockIdx.y == gridDim.y - 1);
  if (edge)
    sdconv_wave<true >(U, V, Wg, Out, b, h0, w0, lane);
  else
    sdconv_wave<false>(U, V, Wg, Out, b, h0, w0, lane);
}

extern "C" void kernel_launch(void* const* d_in, const int* in_sizes, int n_in,
                              void* d_out, int out_size, void* d_ws, size_t ws_size,
                              hipStream_t stream) {
  const float* U  = (const float*)d_in[0];
  const float* V  = (const float*)d_in[1];
  const float* Wg = (const float*)d_in[2];
  float* Out = (float*)d_out;

  dim3 grid(W / 16, H / 16, Bn);  // 14 x 14 x 8 = 1568 blocks
  dim3 block(128);                // 2 waves; each wave: 16w x 8h pixels
  sdconv_mfma<<<grid, block, 0, stream>>>(U, V, Wg, Out);
}